// Round 5
// baseline (346.290 us; speedup 1.0000x reference)
//
#include <hip/hip_runtime.h>

// B=32, DIM=4096, NH=32, NKV=8, HD=128, MAXLEN=4096, START_POS=4095. All fp32.
// HBM floor: KV 1GB + weights 160MB ~= 190us @6.3TB/s.
#define QSCALE 0.08838834764831845f   // 1/sqrt(128)

// ws layout (floats):
//  part_qkv [16][32][6144] @ 0        (3145728)
//  pmss     [32768][2]     @ 3145728  (65536)
//  pacc     [32768][128]   @ 3211264  (4194304)
//  a_ws     [32][4096]     @ 7405568  (131072)
//  part_out [16][32][4096] @ 7536640  (2097152)

// ---------------------------------------------------------------------------
// GEMV: part[ks][n][m0+..] = sum over 256-k slice of W[m][k]*X[n][k].
// (unchanged from round 3/4)
// ---------------------------------------------------------------------------
#define GEMM_FMA(r, wf) \
    acc[r][0] = fmaf(wf.x, x0.x, acc[r][0]); acc[r][0] = fmaf(wf.y, x0.y, acc[r][0]); \
    acc[r][0] = fmaf(wf.z, x0.z, acc[r][0]); acc[r][0] = fmaf(wf.w, x0.w, acc[r][0]); \
    acc[r][1] = fmaf(wf.x, x1.x, acc[r][1]); acc[r][1] = fmaf(wf.y, x1.y, acc[r][1]); \
    acc[r][1] = fmaf(wf.z, x1.z, acc[r][1]); acc[r][1] = fmaf(wf.w, x1.w, acc[r][1]); \
    acc[r][2] = fmaf(wf.x, x2.x, acc[r][2]); acc[r][2] = fmaf(wf.y, x2.y, acc[r][2]); \
    acc[r][2] = fmaf(wf.z, x2.z, acc[r][2]); acc[r][2] = fmaf(wf.w, x2.w, acc[r][2]); \
    acc[r][3] = fmaf(wf.x, x3.x, acc[r][3]); acc[r][3] = fmaf(wf.y, x3.y, acc[r][3]); \
    acc[r][3] = fmaf(wf.z, x3.z, acc[r][3]); acc[r][3] = fmaf(wf.w, x3.w, acc[r][3]);

__device__ __forceinline__ void gemv3(
    const float* __restrict__ W,      // pre-offset: row 0 == output column m0
    const float* __restrict__ X,
    float* __restrict__ part, const int M, const int m0, const int ks)
{
    const int t = threadIdx.x;
    const int ksub = t & 3;
    const int ngrp = (t >> 2) & 7;
    const int mgrp = t >> 5;

    const int kbase = ks * 256 + ksub * 4;
    const float* wr0 = W + (size_t)(mgrp * 8 + 0) * 4096 + kbase;
    const float* wr1 = W + (size_t)(mgrp * 8 + 1) * 4096 + kbase;
    const float* wr2 = W + (size_t)(mgrp * 8 + 2) * 4096 + kbase;
    const float* wr3 = W + (size_t)(mgrp * 8 + 3) * 4096 + kbase;
    const float* wr4 = W + (size_t)(mgrp * 8 + 4) * 4096 + kbase;
    const float* wr5 = W + (size_t)(mgrp * 8 + 5) * 4096 + kbase;
    const float* wr6 = W + (size_t)(mgrp * 8 + 6) * 4096 + kbase;
    const float* wr7 = W + (size_t)(mgrp * 8 + 7) * 4096 + kbase;
    const float* xr0 = X + (size_t)(ngrp * 4 + 0) * 4096 + kbase;
    const float* xr1 = X + (size_t)(ngrp * 4 + 1) * 4096 + kbase;
    const float* xr2 = X + (size_t)(ngrp * 4 + 2) * 4096 + kbase;
    const float* xr3 = X + (size_t)(ngrp * 4 + 3) * 4096 + kbase;

    float acc[8][4];
#pragma unroll
    for (int r = 0; r < 8; ++r)
#pragma unroll
        for (int n = 0; n < 4; ++n) acc[r][n] = 0.f;

#pragma unroll 2
    for (int c = 0; c < 16; ++c) {
        const int off = c * 16;
        const float4 w0 = *(const float4*)(wr0 + off);
        const float4 w1 = *(const float4*)(wr1 + off);
        const float4 w2 = *(const float4*)(wr2 + off);
        const float4 w3 = *(const float4*)(wr3 + off);
        const float4 w4 = *(const float4*)(wr4 + off);
        const float4 w5 = *(const float4*)(wr5 + off);
        const float4 w6 = *(const float4*)(wr6 + off);
        const float4 w7 = *(const float4*)(wr7 + off);
        const float4 x0 = *(const float4*)(xr0 + off);
        const float4 x1 = *(const float4*)(xr1 + off);
        const float4 x2 = *(const float4*)(xr2 + off);
        const float4 x3 = *(const float4*)(xr3 + off);
        GEMM_FMA(0, w0) GEMM_FMA(1, w1) GEMM_FMA(2, w2) GEMM_FMA(3, w3)
        GEMM_FMA(4, w4) GEMM_FMA(5, w5) GEMM_FMA(6, w6) GEMM_FMA(7, w7)
    }

#pragma unroll
    for (int r = 0; r < 8; ++r)
#pragma unroll
        for (int n = 0; n < 4; ++n) {
            acc[r][n] += __shfl_xor(acc[r][n], 1);
            acc[r][n] += __shfl_xor(acc[r][n], 2);
        }

    if (ksub == 0) {
        float* base = part + (size_t)ks * 32 * M + m0 + mgrp * 8;
#pragma unroll
        for (int n = 0; n < 4; ++n) {
            float* dst = base + (size_t)(ngrp * 4 + n) * M;
            *(float4*)(dst)     = make_float4(acc[0][n], acc[1][n], acc[2][n], acc[3][n]);
            *(float4*)(dst + 4) = make_float4(acc[4][n], acc[5][n], acc[6][n], acc[7][n]);
        }
    }
}

__global__ __launch_bounds__(256, 4) void gemv_qkv_kernel(
    const float* __restrict__ wq, const float* __restrict__ wk,
    const float* __restrict__ wv, const float* __restrict__ x,
    float* __restrict__ part)     // [16][32][6144]
{
    const int mb = blockIdx.x >> 4, ks = blockIdx.x & 15;
    const int m0 = mb * 64;
    const float* W;
    if (m0 < 4096)      W = wq + (size_t)m0 * 4096;
    else if (m0 < 5120) W = wk + (size_t)(m0 - 4096) * 4096;
    else                W = wv + (size_t)(m0 - 5120) * 4096;
    gemv3(W, x, part, 6144, m0, ks);
}

__global__ __launch_bounds__(256, 4) void gemv_out_kernel(
    const float* __restrict__ wo, const float* __restrict__ a_ws,
    float* __restrict__ part)     // [16][32][4096]
{
    const int mb = blockIdx.x >> 4, ks = blockIdx.x & 15;
    gemv3(wo + (size_t)(mb * 64) * 4096, a_ws, part, 4096, mb * 64, ks);
}

// ---------------------------------------------------------------------------
// Attention v5: qkv-combine folded into prologue; zero-mov 4-row double-body
// pipeline. grid = 1024: bid = ((b*16 + split)*2 + q2). 256 thr = 4 waves.
// Wave w: gsub = w>>1, rsub = w&1. Lane: g2 = lane>>5, j = lane&31.
// g = q2*4 + gsub*2 + g2; lane owns d-slice j*4. Wave streams 128 rows,
// 1KB contiguous per load instr. Online softmax w/ deferred rescale.
// ---------------------------------------------------------------------------
__global__ __launch_bounds__(256, 4) void attn5_kernel(
    const float* __restrict__ part_qkv,   // [16][32][6144]
    const float* __restrict__ freqs,      // [128]
    const float* __restrict__ cache_k, const float* __restrict__ cache_v,
    float* __restrict__ pmss, float* __restrict__ pacc)
{
    const int t = threadIdx.x;
    const int w = t >> 6, lane = t & 63;
    const int g2 = lane >> 5, j = lane & 31;
    const int bid = blockIdx.x;
    const int q2 = bid & 1, split = (bid >> 1) & 15, b = bid >> 5;
    const int gsub = w >> 1, rsub = w & 1;
    const int g  = q2 * 4 + gsub * 2 + g2;   // kv-group
    const int gl = gsub * 2 + g2;            // local group 0..3
    const int row0 = split * 256 + rsub * 128;

    __shared__ float qc[16][128];     // roped+scaled q for block's 16 heads
    __shared__ float knl[4][128];     // roped new k for block's 4 groups
    __shared__ float vnl[4][128];     // new v

    const size_t PS = 32 * 6144;
    // ---- prologue phase 1: q heads (thread -> head H, 8 d) ----
    {
        const int H = t >> 4, dq = (t & 15) * 8;
        const float* p = part_qkv + (size_t)b * 6144 + (size_t)(q2 * 16 + H) * 128 + dq;
        float4 s0 = make_float4(0.f, 0.f, 0.f, 0.f);
        float4 s1 = make_float4(0.f, 0.f, 0.f, 0.f);
#pragma unroll
        for (int s = 0; s < 16; ++s) {
            const float4 a = *(const float4*)(p + s * PS);
            const float4 c = *(const float4*)(p + s * PS + 4);
            s0.x += a.x; s0.y += a.y; s0.z += a.z; s0.w += a.w;
            s1.x += c.x; s1.y += c.y; s1.z += c.z; s1.w += c.w;
        }
        const float4 f0 = *(const float4*)(freqs + dq);
        const float4 f1 = *(const float4*)(freqs + dq + 4);
        qc[H][dq + 0] = (s0.x * f0.x - s0.y * f0.y) * QSCALE;
        qc[H][dq + 1] = (s0.x * f0.y + s0.y * f0.x) * QSCALE;
        qc[H][dq + 2] = (s0.z * f0.z - s0.w * f0.w) * QSCALE;
        qc[H][dq + 3] = (s0.z * f0.w + s0.w * f0.z) * QSCALE;
        qc[H][dq + 4] = (s1.x * f1.x - s1.y * f1.y) * QSCALE;
        qc[H][dq + 5] = (s1.x * f1.y + s1.y * f1.x) * QSCALE;
        qc[H][dq + 6] = (s1.z * f1.z - s1.w * f1.w) * QSCALE;
        qc[H][dq + 7] = (s1.z * f1.w + s1.w * f1.z) * QSCALE;
    }
    // ---- prologue phase 2: new k (t<128) / new v (t>=128) ----
    {
        const int tv = t & 127;
        const int glp = tv >> 5, d4 = (tv & 31) * 4;
        const int moff = (t < 128 ? 4096 : 5120) + (q2 * 4 + glp) * 128 + d4;
        const float* p = part_qkv + (size_t)b * 6144 + moff;
        float4 s0 = make_float4(0.f, 0.f, 0.f, 0.f);
#pragma unroll
        for (int s = 0; s < 16; ++s) {
            const float4 a = *(const float4*)(p + s * PS);
            s0.x += a.x; s0.y += a.y; s0.z += a.z; s0.w += a.w;
        }
        if (t < 128) {
            const float4 f = *(const float4*)(freqs + d4);
            knl[glp][d4 + 0] = s0.x * f.x - s0.y * f.y;
            knl[glp][d4 + 1] = s0.x * f.y + s0.y * f.x;
            knl[glp][d4 + 2] = s0.z * f.z - s0.w * f.w;
            knl[glp][d4 + 3] = s0.z * f.w + s0.w * f.z;
        } else {
            vnl[glp][d4 + 0] = s0.x; vnl[glp][d4 + 1] = s0.y;
            vnl[glp][d4 + 2] = s0.z; vnl[glp][d4 + 3] = s0.w;
        }
    }
    __syncthreads();

    float4 q[4];
#pragma unroll
    for (int h = 0; h < 4; ++h) q[h] = *(const float4*)&qc[gl * 4 + h][j * 4];

    float m[4]  = {-1e30f, -1e30f, -1e30f, -1e30f};
    float ss[4] = {0.f, 0.f, 0.f, 0.f};
    float4 acc[4];
#pragma unroll
    for (int h = 0; h < 4; ++h) acc[h] = make_float4(0.f, 0.f, 0.f, 0.f);

    auto process = [&](const float4 kf, const float4 vf) {
        float d[4];
#pragma unroll
        for (int h = 0; h < 4; ++h)
            d[h] = fmaf(q[h].x, kf.x, fmaf(q[h].y, kf.y,
                   fmaf(q[h].z, kf.z, q[h].w * kf.w)));
#pragma unroll
        for (int mask = 1; mask <= 16; mask <<= 1) {
            d[0] += __shfl_xor(d[0], mask);
            d[1] += __shfl_xor(d[1], mask);
            d[2] += __shfl_xor(d[2], mask);
            d[3] += __shfl_xor(d[3], mask);
        }
#pragma unroll
        for (int h = 0; h < 4; ++h) {
            const float dd = d[h] - m[h];
            float pe;
            if (dd > 8.0f) {                       // rare: new max by margin
                const float c = __expf(-dd);
                ss[h] = fmaf(ss[h], c, 1.0f);
                acc[h].x *= c; acc[h].y *= c; acc[h].z *= c; acc[h].w *= c;
                m[h] = d[h]; pe = 1.0f;
            } else {
                pe = __expf(dd);                   // <= e^8
                ss[h] += pe;
            }
            acc[h].x = fmaf(pe, vf.x, acc[h].x);
            acc[h].y = fmaf(pe, vf.y, acc[h].y);
            acc[h].z = fmaf(pe, vf.z, acc[h].z);
            acc[h].w = fmaf(pe, vf.w, acc[h].w);
        }
    };

    const size_t cbase = ((size_t)b * 4096 + row0) * 1024 + (size_t)g * 128 + j * 4;
    const float* kp = cache_k + cbase;
    const float* vp = cache_v + cbase;

    const bool lastw = (split == 15) && (rsub == 1);   // owns row 4095
    const int n = lastw ? 127 : 128;

    // zero-mov double-body pipeline: slots A,B / C,D alternate, loads 2+ ahead
    float4 kA, vA, kB, vB, kC, vC, kD, vD;
    kA = *(const float4*)(kp);        vA = *(const float4*)(vp);
    kB = *(const float4*)(kp + 1024); vB = *(const float4*)(vp + 1024);
    int i = 0;
    for (; i + 4 <= n; i += 4) {
        const float* k2 = kp + (size_t)(i + 2) * 1024;
        const float* v2 = vp + (size_t)(i + 2) * 1024;
        kC = *(const float4*)(k2);        vC = *(const float4*)(v2);
        kD = *(const float4*)(k2 + 1024); vD = *(const float4*)(v2 + 1024);
        process(kA, vA);
        process(kB, vB);
        if (i + 6 <= n) {
            const float* k4 = kp + (size_t)(i + 4) * 1024;
            const float* v4 = vp + (size_t)(i + 4) * 1024;
            kA = *(const float4*)(k4);        vA = *(const float4*)(v4);
            kB = *(const float4*)(k4 + 1024); vB = *(const float4*)(v4 + 1024);
        } else if (i + 5 <= n) {
            const float* k4 = kp + (size_t)(i + 4) * 1024;
            const float* v4 = vp + (size_t)(i + 4) * 1024;
            kA = *(const float4*)(k4); vA = *(const float4*)(v4);
        }
        process(kC, vC);
        process(kD, vD);
    }
    if (i < n)     process(kA, vA);
    if (i + 1 < n) process(kB, vB);
    if (i + 2 < n) {
        const float4 kf = *(const float4*)(kp + (size_t)(i + 2) * 1024);
        const float4 vf = *(const float4*)(vp + (size_t)(i + 2) * 1024);
        process(kf, vf);
    }
    if (lastw) {   // row 4095: freshly roped new-token k / new v from LDS
        const float4 kf = *(const float4*)&knl[gl][j * 4];
        const float4 vf = *(const float4*)&vnl[gl][j * 4];
        process(kf, vf);
    }

    // partials: idx = (((b*16+split)*2+rsub)*8 + g)*4 + h
    const int pidx = (((b * 16 + split) * 2 + rsub) * 8 + g) * 4;
#pragma unroll
    for (int h = 0; h < 4; ++h)
        *(float4*)(pacc + (size_t)(pidx + h) * 128 + j * 4) = acc[h];
    if (j == 0) {
#pragma unroll
        for (int h = 0; h < 4; ++h) {
            pmss[(size_t)(pidx + h) * 2]     = m[h];
            pmss[(size_t)(pidx + h) * 2 + 1] = ss[h];
        }
    }
}

// ---------------------------------------------------------------------------
// Merge 32 partials per (b,g,h). Block=(b,g), 128 thr: h=t>>5, jj=t&31.
// ---------------------------------------------------------------------------
__global__ __launch_bounds__(128) void attn_combine_kernel(
    const float* __restrict__ pmss, const float* __restrict__ pacc,
    float* __restrict__ a_ws)
{
    const int bg = blockIdx.x, t = threadIdx.x;
    const int h = t >> 5, jj = t & 31;
    const int b = bg >> 3, g = bg & 7;

    float M = -1e30f;
#pragma unroll
    for (int s = 0; s < 16; ++s)
#pragma unroll
        for (int r = 0; r < 2; ++r) {
            const int idx = (((b * 16 + s) * 2 + r) * 8 + g) * 4 + h;
            M = fmaxf(M, pmss[(size_t)idx * 2]);
        }
    float SS = 0.f;
    float4 o = make_float4(0.f, 0.f, 0.f, 0.f);
#pragma unroll
    for (int s = 0; s < 16; ++s)
#pragma unroll
        for (int r = 0; r < 2; ++r) {
            const int idx = (((b * 16 + s) * 2 + r) * 8 + g) * 4 + h;
            const float wgt = __expf(pmss[(size_t)idx * 2] - M);
            SS = fmaf(pmss[(size_t)idx * 2 + 1], wgt, SS);
            const float4 a = *(const float4*)(pacc + (size_t)idx * 128 + jj * 4);
            o.x = fmaf(a.x, wgt, o.x);
            o.y = fmaf(a.y, wgt, o.y);
            o.z = fmaf(a.z, wgt, o.z);
            o.w = fmaf(a.w, wgt, o.w);
        }
    const float inv = 1.f / SS;
    o.x *= inv; o.y *= inv; o.z *= inv; o.w *= inv;
    *(float4*)(a_ws + (size_t)b * 4096 + (size_t)(g * 4 + h) * 128 + jj * 4) = o;
}

__global__ __launch_bounds__(256) void out_combine_kernel(
    const float* __restrict__ part, float* __restrict__ out)
{
    const int i4 = (blockIdx.x * 256 + threadIdx.x) * 4;
    float4 v = make_float4(0.f, 0.f, 0.f, 0.f);
#pragma unroll
    for (int s = 0; s < 16; ++s) {
        const float4 a = *(const float4*)(part + (size_t)s * 131072 + i4);
        v.x += a.x; v.y += a.y; v.z += a.z; v.w += a.w;
    }
    *(float4*)(out + i4) = v;
}

extern "C" void kernel_launch(void* const* d_in, const int* in_sizes, int n_in,
                              void* d_out, int out_size, void* d_ws, size_t ws_size,
                              hipStream_t stream)
{
    const float* x       = (const float*)d_in[0];
    const float* freqs   = (const float*)d_in[1];
    const float* cache_k = (const float*)d_in[2];
    const float* cache_v = (const float*)d_in[3];
    const float* wq      = (const float*)d_in[4];
    const float* wk      = (const float*)d_in[5];
    const float* wv      = (const float*)d_in[6];
    const float* wo      = (const float*)d_in[7];

    float* out = (float*)d_out;
    float* ws  = (float*)d_ws;
    float* part_qkv = ws;                    // 3145728
    float* pmss     = ws + 3145728;          // 65536
    float* pacc     = ws + 3211264;          // 4194304
    float* a_ws     = ws + 7405568;          // 131072
    float* part_out = ws + 7536640;          // 2097152

    gemv_qkv_kernel<<<1536, 256, 0, stream>>>(wq, wk, wv, x, part_qkv);
    attn5_kernel<<<1024, 256, 0, stream>>>(part_qkv, freqs, cache_k, cache_v, pmss, pacc);
    attn_combine_kernel<<<256, 128, 0, stream>>>(pmss, pacc, a_ws);
    gemv_out_kernel<<<1024, 256, 0, stream>>>(wo, a_ws, part_out);
    out_combine_kernel<<<128, 256, 0, stream>>>(part_out, out);
}